// Round 9
// baseline (349.397 us; speedup 1.0000x reference)
//
#include <hip/hip_runtime.h>
#include <float.h>
#include <math.h>

#define TOKENS 8192
#define EXPERTS 256
#define HIDDEN 7168
#define TOPK 8
#define TOPKG 4

#define BM 128
#define BN 256
#define BK 32
#define KSPLIT 4
#define KQ (HIDDEN / KSPLIT)     // 1792
#define NKTB (KQ / BK)           // 56 k-steps per block

#define TAU_E 6.0e-6f
#define TAU_G 1.2e-5f
#define MAXFB 1024

// ---- ws layouts (bytes) ----
// partial path: P0..P3 [0, 32M) | cnt 33554432 | list +256 | WH 33685504 | WL 37355520 (end ~41M)
// atomic  path: LG [0, 8M) | cnt 8388608 | list +256 | WH 8519680 | WL 12189696
#define WIMG_ELEMS 1835008   // ushorts per buffer: 448 kt16 * 8 cg * 512

typedef __attribute__((ext_vector_type(8))) short bf16x8;
typedef __attribute__((ext_vector_type(16))) float f32x16;

__device__ inline ushort bf16_rne(float x) {
    uint u = __float_as_uint(x);
    return (ushort)((u + 0x7FFFu + ((u >> 16) & 1u)) >> 16);
}
__device__ inline float bf16_tof(ushort h) { return __uint_as_float((uint)h << 16); }

#define CVTPK(lo, hi) ({ uint r_; asm("v_cvt_pk_bf16_f32 %0, %1, %2" : "=v"(r_) : "v"(lo), "v"(hi)); r_; })
__device__ inline float lo16f(uint u) { return __uint_as_float(u << 16); }
__device__ inline float hi16f(uint u) { return __uint_as_float(u & 0xFFFF0000u); }

// Counted-sync barrier (T4): drain only LDS ops; leave global prefetch in flight.
// Compiler still inserts data-dependent vmcnt waits before each load's USE,
// which lands ~1 iteration after issue -> latency hidden, no per-iter drain.
#define BAR() do {                                             \
    asm volatile("s_waitcnt lgkmcnt(0)" ::: "memory");         \
    __builtin_amdgcn_s_barrier();                              \
    __builtin_amdgcn_sched_barrier(0);                         \
} while (0)

// W image, 32x32-MFMA fragment order over the FULL expert dim:
// wh[((kt16*8)+cg)*512 + lane*8 + j] = bf16(W[cg*32+(lane&31)][kt16*16+(lane>>5)*8+j])
__global__ __launch_bounds__(256) void split_w(const float* __restrict__ W,
                                               ushort* __restrict__ wh,
                                               ushort* __restrict__ wl,
                                               int* __restrict__ cnt) {
    if (blockIdx.x == 0 && threadIdx.x == 0) *cnt = 0;
    const int tau  = blockIdx.x * 256 + threadIdx.x;   // [0, 1835008)
    const int j    = tau & 7;
    const int lane = (tau >> 3) & 63;
    const int cg   = (tau >> 9) & 7;
    const int kt16 = tau >> 12;
    const int col  = cg * 32 + (lane & 31);
    const int k    = kt16 * 16 + (lane >> 5) * 8 + j;
    const float w  = W[(size_t)col * HIDDEN + k];
    const ushort h = bf16_rne(w);
    const ushort l = bf16_rne(w - bf16_tof(h));
    wh[tau] = h;
    wl[tau] = l;
}

// ---------------- bf16-split 32x32 MFMA GEMM ----------------
// Grid 256 = 64 mb x 4 ks (b = mb*4+ks -> each XCD hosts ONE ks W-slice, L2-resident).
// 512 threads, 8 waves (2 wm x 4 wn), wave tile 64x64. A via LDS dbuf (cvt_pk
// split in-kernel); W fragments direct from the pre-split L2 image.
template <bool ATOMIC>
__global__ __launch_bounds__(512, 2) void logits_mfma(const float* __restrict__ A,
                                                      const ushort* __restrict__ wh,
                                                      const ushort* __restrict__ wl,
                                                      float* __restrict__ dst) {
    __shared__ ushort Ah[2][BM * BK];   // 8KB per buf
    __shared__ ushort Al[2][BM * BK];

    const int b  = blockIdx.x;
    const int ks = b & 3;
    const int mb = b >> 2;
    const int row0 = mb * BM;

    const int t = threadIdx.x, lane = t & 63, wid = t >> 6;
    const int wm = wid >> 2, wn = wid & 3;

    // A staging: thread t -> row sr=t>>2, octet q=t&3 (8 floats)
    const int sr = t >> 2, q = t & 3;
    const float* Ap = A + (size_t)(row0 + sr) * HIDDEN + (size_t)ks * KQ + q * 8;
    const int sswz = ((sr >> 1) ^ (sr >> 3)) & 3;
    const int sidx = sr * 32 + ((q ^ sswz) << 3);

    // A fragment read indices [mi][kh]
    int fidx[2][2];
    #pragma unroll
    for (int mi = 0; mi < 2; ++mi) {
        const int r = wm * 64 + mi * 32 + (lane & 31);
        const int swz = ((r >> 1) ^ (r >> 3)) & 3;
        #pragma unroll
        for (int kh = 0; kh < 2; ++kh)
            fidx[mi][kh] = r * 32 + (((kh * 2 + (lane >> 5)) ^ swz) << 3);
    }

    const int wlanes = lane * 8;

    f32x16 acc[2][2];
    #pragma unroll
    for (int mi = 0; mi < 2; ++mi)
        #pragma unroll
        for (int n = 0; n < 2; ++n) acc[mi][n] = (f32x16)0.f;

    float4 aA0, aA1, aB0, aB1;
    bf16x8 wAh[2][2], wAl[2][2], wBh[2][2], wBl[2][2];   // [n][kh]

    #define WLOAD(DH, DL, KTL) do {                                            \
        const size_t wo = ((size_t)((ks * NKTB + (KTL)) * 16 + wn * 2)) * 512 + wlanes; \
        DH[0][0] = *(const bf16x8*)(wh + wo);                                  \
        DH[1][0] = *(const bf16x8*)(wh + wo + 512);                            \
        DH[0][1] = *(const bf16x8*)(wh + wo + 4096);                           \
        DH[1][1] = *(const bf16x8*)(wh + wo + 4608);                           \
        DL[0][0] = *(const bf16x8*)(wl + wo);                                  \
        DL[1][0] = *(const bf16x8*)(wl + wo + 512);                            \
        DL[0][1] = *(const bf16x8*)(wl + wo + 4096);                           \
        DL[1][1] = *(const bf16x8*)(wl + wo + 4608);                           \
    } while (0)

    #define STAGE(BB, R0, R1) do {                                             \
        uint h0 = CVTPK(R0.x, R0.y), h1 = CVTPK(R0.z, R0.w);                   \
        uint h2 = CVTPK(R1.x, R1.y), h3 = CVTPK(R1.z, R1.w);                   \
        float q0 = R0.x - lo16f(h0), q1 = R0.y - hi16f(h0);                    \
        float q2 = R0.z - lo16f(h1), q3 = R0.w - hi16f(h1);                    \
        float q4 = R1.x - lo16f(h2), q5 = R1.y - hi16f(h2);                    \
        float q6 = R1.z - lo16f(h3), q7 = R1.w - hi16f(h3);                    \
        uint l0 = CVTPK(q0, q1), l1 = CVTPK(q2, q3);                           \
        uint l2 = CVTPK(q4, q5), l3 = CVTPK(q6, q7);                           \
        *(uint4*)&Ah[BB][sidx] = make_uint4(h0, h1, h2, h3);                   \
        *(uint4*)&Al[BB][sidx] = make_uint4(l0, l1, l2, l3);                   \
    } while (0)

    #define ALOAD(R0, R1, KTL) do {                                            \
        const int ka = ((KTL) < NKTB ? (KTL) : NKTB - 1) * BK;                 \
        R0 = *(const float4*)(Ap + ka);                                        \
        R1 = *(const float4*)(Ap + ka + 4);                                    \
    } while (0)

    #define MF __builtin_amdgcn_mfma_f32_32x32x16_bf16

    #define ITER(KT, BB, X0, X1, WXH, WXL, WYH, WYL) do {                      \
        BAR();                                                                 \
        bf16x8 afh[2][2], afl[2][2];                                           \
        afh[0][0] = *(const bf16x8*)&Ah[BB][fidx[0][0]];                       \
        afh[0][1] = *(const bf16x8*)&Ah[BB][fidx[0][1]];                       \
        afh[1][0] = *(const bf16x8*)&Ah[BB][fidx[1][0]];                       \
        afh[1][1] = *(const bf16x8*)&Ah[BB][fidx[1][1]];                       \
        afl[0][0] = *(const bf16x8*)&Al[BB][fidx[0][0]];                       \
        afl[0][1] = *(const bf16x8*)&Al[BB][fidx[0][1]];                       \
        afl[1][0] = *(const bf16x8*)&Al[BB][fidx[1][0]];                       \
        afl[1][1] = *(const bf16x8*)&Al[BB][fidx[1][1]];                       \
        STAGE((BB) ^ 1, X0, X1);                                               \
        ALOAD(X0, X1, (KT) + 3);                                               \
        WLOAD(WYH, WYL, ((KT) + 1 < NKTB ? (KT) + 1 : NKTB - 1));              \
        acc[0][0] = MF(afh[0][0], WXH[0][0], acc[0][0], 0, 0, 0);              \
        acc[0][0] = MF(afl[0][0], WXH[0][0], acc[0][0], 0, 0, 0);              \
        acc[0][0] = MF(afh[0][0], WXL[0][0], acc[0][0], 0, 0, 0);              \
        acc[0][1] = MF(afh[0][0], WXH[1][0], acc[0][1], 0, 0, 0);              \
        acc[0][1] = MF(afl[0][0], WXH[1][0], acc[0][1], 0, 0, 0);              \
        acc[0][1] = MF(afh[0][0], WXL[1][0], acc[0][1], 0, 0, 0);              \
        acc[1][0] = MF(afh[1][0], WXH[0][0], acc[1][0], 0, 0, 0);              \
        acc[1][0] = MF(afl[1][0], WXH[0][0], acc[1][0], 0, 0, 0);              \
        acc[1][0] = MF(afh[1][0], WXL[0][0], acc[1][0], 0, 0, 0);              \
        acc[1][1] = MF(afh[1][0], WXH[1][0], acc[1][1], 0, 0, 0);              \
        acc[1][1] = MF(afl[1][0], WXH[1][0], acc[1][1], 0, 0, 0);              \
        acc[1][1] = MF(afh[1][0], WXL[1][0], acc[1][1], 0, 0, 0);              \
        acc[0][0] = MF(afh[0][1], WXH[0][1], acc[0][0], 0, 0, 0);              \
        acc[0][0] = MF(afl[0][1], WXH[0][1], acc[0][0], 0, 0, 0);              \
        acc[0][0] = MF(afh[0][1], WXL[0][1], acc[0][0], 0, 0, 0);              \
        acc[0][1] = MF(afh[0][1], WXH[1][1], acc[0][1], 0, 0, 0);              \
        acc[0][1] = MF(afl[0][1], WXH[1][1], acc[0][1], 0, 0, 0);              \
        acc[0][1] = MF(afh[0][1], WXL[1][1], acc[0][1], 0, 0, 0);              \
        acc[1][0] = MF(afh[1][1], WXH[0][1], acc[1][0], 0, 0, 0);              \
        acc[1][0] = MF(afl[1][1], WXH[0][1], acc[1][0], 0, 0, 0);              \
        acc[1][0] = MF(afh[1][1], WXL[0][1], acc[1][0], 0, 0, 0);              \
        acc[1][1] = MF(afh[1][1], WXH[1][1], acc[1][1], 0, 0, 0);              \
        acc[1][1] = MF(afl[1][1], WXH[1][1], acc[1][1], 0, 0, 0);              \
        acc[1][1] = MF(afh[1][1], WXL[1][1], acc[1][1], 0, 0, 0);              \
    } while (0)

    // prologue
    ALOAD(aA0, aA1, 0);
    STAGE(0, aA0, aA1);
    ALOAD(aA0, aA1, 1);
    ALOAD(aB0, aB1, 2);
    WLOAD(wAh, wAl, 0);

    for (int kt2 = 0; kt2 < NKTB; kt2 += 2) {
        ITER(kt2,     0, aA0, aA1, wAh, wAl, wBh, wBl);
        ITER(kt2 + 1, 1, aB0, aB1, wBh, wBl, wAh, wAl);
    }

    // epilogue: C/D col=lane&31, row=(g&3)+8*(g>>2)+4*(lane>>5)  [m74/m101]
    float* o = ATOMIC ? dst : dst + (size_t)ks * TOKENS * EXPERTS;
    #pragma unroll
    for (int mi = 0; mi < 2; ++mi)
        #pragma unroll
        for (int n = 0; n < 2; ++n)
            #pragma unroll
            for (int g = 0; g < 16; ++g) {
                const int row = row0 + wm * 64 + mi * 32 + (g & 3) + ((g >> 2) << 3) + ((lane >> 5) << 2);
                const int col = wn * 64 + n * 32 + (lane & 31);
                const size_t idx = (size_t)row * EXPERTS + col;
                if (ATOMIC) atomicAdd(o + idx, acc[mi][n][g]);
                else        o[idx] = acc[mi][n][g];
            }
    #undef ITER
    #undef MF
    #undef ALOAD
    #undef STAGE
    #undef WLOAD
}

// ---------------- fast route with decision margins ----------------
template <int NPART>
__global__ __launch_bounds__(256) void route_margin(const float* __restrict__ p0,
                                                    const float* __restrict__ bias,
                                                    float* __restrict__ out,
                                                    int* __restrict__ cnt,
                                                    int* __restrict__ list) {
    const int lane = threadIdx.x & 63;
    const int t    = blockIdx.x * 4 + (threadIdx.x >> 6);

    float4 lg = *(const float4*)(p0 + (size_t)t * EXPERTS + (lane << 2));
    #pragma unroll
    for (int p = 1; p < NPART; ++p) {
        const float4 l2 = *(const float4*)(p0 + (size_t)p * TOKENS * EXPERTS +
                                           (size_t)t * EXPERTS + (lane << 2));
        lg.x += l2.x; lg.y += l2.y; lg.z += l2.z; lg.w += l2.w;
    }
    const float4 bz = *(const float4*)(bias + (lane << 2));

    const float s0 = 1.f / (1.f + expf(-lg.x));
    const float s1 = 1.f / (1.f + expf(-lg.y));
    const float s2 = 1.f / (1.f + expf(-lg.z));
    const float s3 = 1.f / (1.f + expf(-lg.w));
    const float b0 = s0 + bz.x, b1 = s1 + bz.y, b2 = s2 + bz.z, b3 = s3 + bz.w;

    float hi01 = fmaxf(b0, b1), lo01 = fminf(b0, b1);
    float hi23 = fmaxf(b2, b3), lo23 = fminf(b2, b3);
    float a0v = fmaxf(hi01, hi23);
    float a1v = fmaxf(fminf(hi01, hi23), fmaxf(lo01, lo23));
    #pragma unroll
    for (int off = 1; off < 8; off <<= 1) {
        float o0 = __shfl_xor(a0v, off);
        float o1 = __shfl_xor(a1v, off);
        float n0 = fmaxf(a0v, o0);
        float n1 = fmaxf(fminf(a0v, o0), fmaxf(a1v, o1));
        a0v = n0; a1v = n1;
    }
    const float gscore = a0v + a1v;

    float gsc[8];
    #pragma unroll
    for (int g = 0; g < 8; ++g) gsc[g] = __shfl(gscore, g << 3);

    const int g0 = lane >> 3;
    int myrank = 0;
    float v4 = -1e30f, v5 = -1e30f;
    #pragma unroll
    for (int h = 0; h < 8; ++h) {
        int rk = 0;
        #pragma unroll
        for (int h2 = 0; h2 < 8; ++h2)
            rk += ((gsc[h2] > gsc[h]) || (gsc[h2] == gsc[h] && h2 < h)) ? 1 : 0;
        if (h == g0) myrank = rk;
        if (rk == TOPKG - 1) v4 = gsc[h];
        if (rk == TOPKG)     v5 = gsc[h];
    }
    const bool sel = (myrank < TOPKG);
    const float margin_g = v4 - v5;

    float m0 = sel ? b0 : 0.f;
    float m1 = sel ? b1 : 0.f;
    float m2 = sel ? b2 : 0.f;
    float m3 = sel ? b3 : 0.f;

    float sum = 0.f;
    int myidx = 0; float mysc = 0.f;
    float prev = 0.f, mine = 1e30f;
    #pragma unroll
    for (int rr = 0; rr < TOPK + 1; ++rr) {
        float bv = m0; int bj = 0;
        if (m1 > bv) { bv = m1; bj = 1; }
        if (m2 > bv) { bv = m2; bj = 2; }
        if (m3 > bv) { bv = m3; bj = 3; }
        float bsc = (bj == 0) ? s0 : (bj == 1) ? s1 : (bj == 2) ? s2 : s3;
        int bidx = (lane << 2) | bj;
        #pragma unroll
        for (int off = 1; off < 64; off <<= 1) {
            float ov  = __shfl_xor(bv, off);
            int   oi  = __shfl_xor(bidx, off);
            float osc = __shfl_xor(bsc, off);
            if (ov > bv || (ov == bv && oi < bidx)) { bv = ov; bidx = oi; bsc = osc; }
        }
        if (rr) mine = fminf(mine, prev - bv);
        prev = bv;
        if (rr < TOPK) {
            sum += bsc;
            if (lane == rr) { myidx = bidx; mysc = bsc; }
            if ((bidx >> 2) == lane) {
                const int sl = bidx & 3;
                if      (sl == 0) m0 = -FLT_MAX;
                else if (sl == 1) m1 = -FLT_MAX;
                else if (sl == 2) m2 = -FLT_MAX;
                else              m3 = -FLT_MAX;
            }
        }
    }

    const bool fb = (margin_g < TAU_G) || (mine < TAU_E);
    if (fb) {
        if (lane == 0) { int p = atomicAdd(cnt, 1); if (p < MAXFB) list[p] = t; }
    } else if (lane < TOPK) {
        const size_t base = (size_t)t * TOPK + lane;
        out[base] = (float)myidx;
        out[(size_t)TOKENS * TOPK + base] = mysc / (sum + 1e-20f) * 2.5f;
    }
}

// ---------------- f1: exact f64 logits for flagged tokens ----------------
// 512 threads, 4 tokens/block (112KB LDS); wave wv owns experts wv*32+ei;
// W rows read fully coalesced, once per block (4 tokens amortize).
__global__ __launch_bounds__(512, 1) void fallback_logits(const float* __restrict__ A,
                                                          const float* __restrict__ W,
                                                          const int* __restrict__ cnt,
                                                          const int* __restrict__ list,
                                                          double* __restrict__ lgs) {
    __shared__ float As[4][HIDDEN];   // 112KB
    const int n = min(*cnt, MAXFB);
    const int base = blockIdx.x * 4;
    if (base >= n) return;
    const int tid = threadIdx.x;
    int tok[4];
    #pragma unroll
    for (int i = 0; i < 4; ++i) tok[i] = (base + i < n) ? list[base + i] : list[base];

    #pragma unroll
    for (int i = 0; i < 4; ++i) {
        const float4* ag = (const float4*)(A + (size_t)tok[i] * HIDDEN);
        for (int p = tid; p < HIDDEN / 4; p += 512)
            ((float4*)As[i])[p] = ag[p];
    }
    __syncthreads();

    const int lane = tid & 63, wv = tid >> 6;
    for (int ei = 0; ei < 32; ++ei) {
        const int e = wv * 32 + ei;
        const float* wr = W + (size_t)e * HIDDEN;
        double ac0 = 0.0, ac1 = 0.0, ac2 = 0.0, ac3 = 0.0;
        #pragma unroll 2
        for (int it = 0; it < HIDDEN / 256; ++it) {   // 28 iterations
            const int k = it * 256 + (lane << 2);
            const float4 w4 = *(const float4*)(wr + k);
            const float4 x0 = *(const float4*)&As[0][k];
            const float4 x1 = *(const float4*)&As[1][k];
            const float4 x2 = *(const float4*)&As[2][k];
            const float4 x3 = *(const float4*)&As[3][k];
            ac0 = fma((double)x0.x, (double)w4.x, ac0);
            ac0 = fma((double)x0.y, (double)w4.y, ac0);
            ac0 = fma((double)x0.z, (double)w4.z, ac0);
            ac0 = fma((double)x0.w, (double)w4.w, ac0);
            ac1 = fma((double)x1.x, (double)w4.x, ac1);
            ac1 = fma((double)x1.y, (double)w4.y, ac1);
            ac1 = fma((double)x1.z, (double)w4.z, ac1);
            ac1 = fma((double)x1.w, (double)w4.w, ac1);
            ac2 = fma((double)x2.x, (double)w4.x, ac2);
            ac2 = fma((double)x2.y, (double)w4.y, ac2);
            ac2 = fma((double)x2.z, (double)w4.z, ac2);
            ac2 = fma((double)x2.w, (double)w4.w, ac2);
            ac3 = fma((double)x3.x, (double)w4.x, ac3);
            ac3 = fma((double)x3.y, (double)w4.y, ac3);
            ac3 = fma((double)x3.z, (double)w4.z, ac3);
            ac3 = fma((double)x3.w, (double)w4.w, ac3);
        }
        #pragma unroll
        for (int off = 32; off; off >>= 1) {
            ac0 += __shfl_xor(ac0, off);
            ac1 += __shfl_xor(ac1, off);
            ac2 += __shfl_xor(ac2, off);
            ac3 += __shfl_xor(ac3, off);
        }
        if (lane == 0) {
            lgs[(size_t)base * EXPERTS + e] = ac0;
            if (base + 1 < n) lgs[(size_t)(base + 1) * EXPERTS + e] = ac1;
            if (base + 2 < n) lgs[(size_t)(base + 2) * EXPERTS + e] = ac2;
            if (base + 3 < n) lgs[(size_t)(base + 3) * EXPERTS + e] = ac3;
        }
    }
}

// ---------------- f2: exact f64 route for flagged tokens ----------------
__global__ __launch_bounds__(256) void fallback_route(const double* __restrict__ lgs,
                                                      const float* __restrict__ bias,
                                                      const int* __restrict__ cnt,
                                                      const int* __restrict__ list,
                                                      float* __restrict__ out) {
    const int n  = min(*cnt, MAXFB);
    const int ti = blockIdx.x * 4 + (threadIdx.x >> 6);
    if (ti >= n) return;
    const int lane = threadIdx.x & 63;
    const int t = list[ti];

    const double l0 = lgs[(size_t)ti * EXPERTS + (lane << 2)];
    const double l1 = lgs[(size_t)ti * EXPERTS + (lane << 2) + 1];
    const double l2 = lgs[(size_t)ti * EXPERTS + (lane << 2) + 2];
    const double l3 = lgs[(size_t)ti * EXPERTS + (lane << 2) + 3];
    const float4 bzf = *(const float4*)(bias + (lane << 2));

    const double s0 = 1.0 / (1.0 + exp(-l0));
    const double s1 = 1.0 / (1.0 + exp(-l1));
    const double s2 = 1.0 / (1.0 + exp(-l2));
    const double s3 = 1.0 / (1.0 + exp(-l3));
    const double b0 = s0 + (double)bzf.x, b1 = s1 + (double)bzf.y;
    const double b2 = s2 + (double)bzf.z, b3 = s3 + (double)bzf.w;

    double hi01 = fmax(b0, b1), lo01 = fmin(b0, b1);
    double hi23 = fmax(b2, b3), lo23 = fmin(b2, b3);
    double a0v = fmax(hi01, hi23);
    double a1v = fmax(fmin(hi01, hi23), fmax(lo01, lo23));
    #pragma unroll
    for (int off = 1; off < 8; off <<= 1) {
        double o0 = __shfl_xor(a0v, off);
        double o1 = __shfl_xor(a1v, off);
        double n0 = fmax(a0v, o0);
        double n1 = fmax(fmin(a0v, o0), fmax(a1v, o1));
        a0v = n0; a1v = n1;
    }
    const double gscore = a0v + a1v;
    double gsc[8];
    #pragma unroll
    for (int g = 0; g < 8; ++g) gsc[g] = __shfl(gscore, g << 3);
    const int g0 = lane >> 3;
    int rank = 0;
    #pragma unroll
    for (int h = 0; h < 8; ++h)
        rank += ((gsc[h] > gscore) || (gsc[h] == gscore && h < g0)) ? 1 : 0;
    const bool sel = (rank < TOPKG);

    double m0 = sel ? b0 : 0.0;
    double m1 = sel ? b1 : 0.0;
    double m2 = sel ? b2 : 0.0;
    double m3 = sel ? b3 : 0.0;

    double sum = 0.0;
    int myidx = 0; double mysc = 0.0;
    #pragma unroll
    for (int rr = 0; rr < TOPK; ++rr) {
        double bv = m0; int bj = 0;
        if (m1 > bv) { bv = m1; bj = 1; }
        if (m2 > bv) { bv = m2; bj = 2; }
        if (m3 > bv) { bv = m3; bj = 3; }
        double bsc = (bj == 0) ? s0 : (bj == 1) ? s1 : (bj == 2) ? s2 : s3;
        int bidx = (lane << 2) | bj;
        #pragma unroll
        for (int off = 1; off < 64; off <<= 1) {
            double ov  = __shfl_xor(bv, off);
            int    oi  = __shfl_xor(bidx, off);
            double osc = __shfl_xor(bsc, off);
            if (ov > bv || (ov == bv && oi < bidx)) { bv = ov; bidx = oi; bsc = osc; }
        }
        sum += bsc;
        if (lane == rr) { myidx = bidx; mysc = bsc; }
        if ((bidx >> 2) == lane) {
            const int sl = bidx & 3;
            if      (sl == 0) m0 = -DBL_MAX;
            else if (sl == 1) m1 = -DBL_MAX;
            else if (sl == 2) m2 = -DBL_MAX;
            else              m3 = -DBL_MAX;
        }
    }
    if (lane < TOPK) {
        const size_t base = (size_t)t * TOPK + lane;
        out[base] = (float)myidx;
        out[(size_t)TOKENS * TOPK + base] = (float)(mysc / (sum + 1e-20) * 2.5);
    }
}

extern "C" void kernel_launch(void* const* d_in, const int* in_sizes, int n_in,
                              void* d_out, int out_size, void* d_ws, size_t ws_size,
                              hipStream_t stream) {
    const float* hs   = (const float*)d_in[0];
    const float* wt   = (const float*)d_in[1];
    const float* bias = (const float*)d_in[2];
    float* out = (float*)d_out;
    char* ws = (char*)d_ws;

    const size_t LGSZ = (size_t)TOKENS * EXPERTS * 4;     // 8 MB
    const size_t WIMG = (size_t)WIMG_ELEMS * 2;           // 3.67 MB per buffer

    if (ws_size >= KSPLIT * LGSZ + 131072 + 2 * WIMG) {
        // deterministic 4-partial path
        float*  part  = (float*)ws;
        int*    cnt   = (int*)(ws + KSPLIT * LGSZ);
        int*    list  = (int*)(ws + KSPLIT * LGSZ + 256);
        ushort* wsh   = (ushort*)(ws + KSPLIT * LGSZ + 131072);
        ushort* wsl   = (ushort*)(ws + KSPLIT * LGSZ + 131072 + WIMG);
        double* lgs64 = (double*)ws;   // overlays P0 after route

        split_w<<<WIMG_ELEMS / 256, 256, 0, stream>>>(wt, wsh, wsl, cnt);
        logits_mfma<false><<<256, 512, 0, stream>>>(hs, wsh, wsl, part);
        route_margin<KSPLIT><<<TOKENS / 4, 256, 0, stream>>>(part, bias, out, cnt, list);
        fallback_logits<<<MAXFB / 4, 512, 0, stream>>>(hs, wt, cnt, list, lgs64);
        fallback_route<<<MAXFB / 4, 256, 0, stream>>>(lgs64, bias, cnt, list, out);
    } else {
        // atomic single-buffer path
        float*  logits = (float*)ws;
        int*    cnt    = (int*)(ws + LGSZ);
        int*    list   = (int*)(ws + LGSZ + 256);
        ushort* wsh    = (ushort*)(ws + LGSZ + 131072);
        ushort* wsl    = (ushort*)(ws + LGSZ + 131072 + WIMG);
        double* lgs64  = (double*)ws;

        hipMemsetAsync(logits, 0, LGSZ, stream);
        split_w<<<WIMG_ELEMS / 256, 256, 0, stream>>>(wt, wsh, wsl, cnt);
        logits_mfma<true><<<256, 512, 0, stream>>>(hs, wsh, wsl, logits);
        route_margin<1><<<TOKENS / 4, 256, 0, stream>>>(logits, bias, out, cnt, list);
        fallback_logits<<<MAXFB / 4, 512, 0, stream>>>(hs, wt, cnt, list, lgs64);
        fallback_route<<<MAXFB / 4, 256, 0, stream>>>(lgs64, bias, cnt, list, out);
    }
}

// Round 10
// 211.937 us; speedup vs baseline: 1.6486x; 1.6486x over previous
//
#include <hip/hip_runtime.h>
#include <float.h>
#include <math.h>

#define TOKENS 8192
#define EXPERTS 256
#define HIDDEN 7168
#define TOPK 8
#define TOPKG 4

#define BM 128
#define BN 256
#define BK 32
#define KSPLIT 4
#define KQ (HIDDEN / KSPLIT)     // 1792
#define NKTB (KQ / BK)           // 56 k-steps per block

#define TAU_E 6.0e-6f
#define TAU_G 1.2e-5f
#define MAXFB 1024

// ---- ws layouts (bytes) ----
// partial path: P0..P3 [0, 32M) | cnt 33554432 | list +256 | WH 33685504 | WL 37355520 (end ~41M)
// atomic  path: LG [0, 8M) | cnt 8388608 | list +256 | WH 8519680 | WL 12189696
#define WIMG_ELEMS 1835008   // ushorts per buffer: 448 kt16 * 8 cg * 512

typedef __attribute__((ext_vector_type(8))) short bf16x8;
typedef __attribute__((ext_vector_type(16))) float f32x16;

__device__ inline ushort bf16_rne(float x) {
    uint u = __float_as_uint(x);
    return (ushort)((u + 0x7FFFu + ((u >> 16) & 1u)) >> 16);
}
__device__ inline float bf16_tof(ushort h) { return __uint_as_float((uint)h << 16); }

#define CVTPK(lo, hi) ({ uint r_; asm("v_cvt_pk_bf16_f32 %0, %1, %2" : "=v"(r_) : "v"(lo), "v"(hi)); r_; })
__device__ inline float lo16f(uint u) { return __uint_as_float(u << 16); }
__device__ inline float hi16f(uint u) { return __uint_as_float(u & 0xFFFF0000u); }

// Counted-sync barrier (T4): drain only LDS ops; leave global prefetch in flight.
#define BAR() do {                                             \
    asm volatile("s_waitcnt lgkmcnt(0)" ::: "memory");         \
    __builtin_amdgcn_s_barrier();                              \
    __builtin_amdgcn_sched_barrier(0);                         \
} while (0)

// W image, 32x32-MFMA fragment order over the FULL expert dim:
// wh[((kt16*8)+cg)*512 + lane*8 + j] = bf16(W[cg*32+(lane&31)][kt16*16+(lane>>5)*8+j])
__global__ __launch_bounds__(256) void split_w(const float* __restrict__ W,
                                               ushort* __restrict__ wh,
                                               ushort* __restrict__ wl,
                                               int* __restrict__ cnt) {
    if (blockIdx.x == 0 && threadIdx.x == 0) *cnt = 0;
    const int tau  = blockIdx.x * 256 + threadIdx.x;   // [0, 1835008)
    const int j    = tau & 7;
    const int lane = (tau >> 3) & 63;
    const int cg   = (tau >> 9) & 7;
    const int kt16 = tau >> 12;
    const int col  = cg * 32 + (lane & 31);
    const int k    = kt16 * 16 + (lane >> 5) * 8 + j;
    const float w  = W[(size_t)col * HIDDEN + k];
    const ushort h = bf16_rne(w);
    const ushort l = bf16_rne(w - bf16_tof(h));
    wh[tau] = h;
    wl[tau] = l;
}

// ---------------- bf16-split 32x32 MFMA GEMM ----------------
// Grid 256 = 64 mb x 4 ks. 512 threads, 8 waves, wave tile 64x64. A via LDS
// dbuf (cvt_pk split in-kernel); W fragments direct from the pre-split L2 image.
template <bool ATOMIC>
__global__ __launch_bounds__(512, 2) void logits_mfma(const float* __restrict__ A,
                                                      const ushort* __restrict__ wh,
                                                      const ushort* __restrict__ wl,
                                                      float* __restrict__ dst) {
    __shared__ ushort Ah[2][BM * BK];   // 8KB per buf
    __shared__ ushort Al[2][BM * BK];

    const int b  = blockIdx.x;
    const int ks = b & 3;
    const int mb = b >> 2;
    const int row0 = mb * BM;

    const int t = threadIdx.x, lane = t & 63, wid = t >> 6;
    const int wm = wid >> 2, wn = wid & 3;

    const int sr = t >> 2, q = t & 3;
    const float* Ap = A + (size_t)(row0 + sr) * HIDDEN + (size_t)ks * KQ + q * 8;
    const int sswz = ((sr >> 1) ^ (sr >> 3)) & 3;
    const int sidx = sr * 32 + ((q ^ sswz) << 3);

    int fidx[2][2];
    #pragma unroll
    for (int mi = 0; mi < 2; ++mi) {
        const int r = wm * 64 + mi * 32 + (lane & 31);
        const int swz = ((r >> 1) ^ (r >> 3)) & 3;
        #pragma unroll
        for (int kh = 0; kh < 2; ++kh)
            fidx[mi][kh] = r * 32 + (((kh * 2 + (lane >> 5)) ^ swz) << 3);
    }

    const int wlanes = lane * 8;

    f32x16 acc[2][2];
    #pragma unroll
    for (int mi = 0; mi < 2; ++mi)
        #pragma unroll
        for (int n = 0; n < 2; ++n) acc[mi][n] = (f32x16)0.f;

    float4 aA0, aA1, aB0, aB1;
    bf16x8 wAh[2][2], wAl[2][2], wBh[2][2], wBl[2][2];   // [n][kh]

    #define WLOAD(DH, DL, KTL) do {                                            \
        const size_t wo = ((size_t)((ks * NKTB + (KTL)) * 16 + wn * 2)) * 512 + wlanes; \
        DH[0][0] = *(const bf16x8*)(wh + wo);                                  \
        DH[1][0] = *(const bf16x8*)(wh + wo + 512);                            \
        DH[0][1] = *(const bf16x8*)(wh + wo + 4096);                           \
        DH[1][1] = *(const bf16x8*)(wh + wo + 4608);                           \
        DL[0][0] = *(const bf16x8*)(wl + wo);                                  \
        DL[1][0] = *(const bf16x8*)(wl + wo + 512);                            \
        DL[0][1] = *(const bf16x8*)(wl + wo + 4096);                           \
        DL[1][1] = *(const bf16x8*)(wl + wo + 4608);                           \
    } while (0)

    #define STAGE(BB, R0, R1) do {                                             \
        uint h0 = CVTPK(R0.x, R0.y), h1 = CVTPK(R0.z, R0.w);                   \
        uint h2 = CVTPK(R1.x, R1.y), h3 = CVTPK(R1.z, R1.w);                   \
        float q0 = R0.x - lo16f(h0), q1 = R0.y - hi16f(h0);                    \
        float q2 = R0.z - lo16f(h1), q3 = R0.w - hi16f(h1);                    \
        float q4 = R1.x - lo16f(h2), q5 = R1.y - hi16f(h2);                    \
        float q6 = R1.z - lo16f(h3), q7 = R1.w - hi16f(h3);                    \
        uint l0 = CVTPK(q0, q1), l1 = CVTPK(q2, q3);                           \
        uint l2 = CVTPK(q4, q5), l3 = CVTPK(q6, q7);                           \
        *(uint4*)&Ah[BB][sidx] = make_uint4(h0, h1, h2, h3);                   \
        *(uint4*)&Al[BB][sidx] = make_uint4(l0, l1, l2, l3);                   \
    } while (0)

    #define ALOAD(R0, R1, KTL) do {                                            \
        const int ka = ((KTL) < NKTB ? (KTL) : NKTB - 1) * BK;                 \
        R0 = *(const float4*)(Ap + ka);                                        \
        R1 = *(const float4*)(Ap + ka + 4);                                    \
    } while (0)

    #define MF __builtin_amdgcn_mfma_f32_32x32x16_bf16

    #define ITER(KT, BB, X0, X1, WXH, WXL, WYH, WYL) do {                      \
        BAR();                                                                 \
        bf16x8 afh[2][2], afl[2][2];                                           \
        afh[0][0] = *(const bf16x8*)&Ah[BB][fidx[0][0]];                       \
        afh[0][1] = *(const bf16x8*)&Ah[BB][fidx[0][1]];                       \
        afh[1][0] = *(const bf16x8*)&Ah[BB][fidx[1][0]];                       \
        afh[1][1] = *(const bf16x8*)&Ah[BB][fidx[1][1]];                       \
        afl[0][0] = *(const bf16x8*)&Al[BB][fidx[0][0]];                       \
        afl[0][1] = *(const bf16x8*)&Al[BB][fidx[0][1]];                       \
        afl[1][0] = *(const bf16x8*)&Al[BB][fidx[1][0]];                       \
        afl[1][1] = *(const bf16x8*)&Al[BB][fidx[1][1]];                       \
        STAGE((BB) ^ 1, X0, X1);                                               \
        ALOAD(X0, X1, (KT) + 3);                                               \
        WLOAD(WYH, WYL, ((KT) + 1 < NKTB ? (KT) + 1 : NKTB - 1));              \
        acc[0][0] = MF(afh[0][0], WXH[0][0], acc[0][0], 0, 0, 0);              \
        acc[0][0] = MF(afl[0][0], WXH[0][0], acc[0][0], 0, 0, 0);              \
        acc[0][0] = MF(afh[0][0], WXL[0][0], acc[0][0], 0, 0, 0);              \
        acc[0][1] = MF(afh[0][0], WXH[1][0], acc[0][1], 0, 0, 0);              \
        acc[0][1] = MF(afl[0][0], WXH[1][0], acc[0][1], 0, 0, 0);              \
        acc[0][1] = MF(afh[0][0], WXL[1][0], acc[0][1], 0, 0, 0);              \
        acc[1][0] = MF(afh[1][0], WXH[0][0], acc[1][0], 0, 0, 0);              \
        acc[1][0] = MF(afl[1][0], WXH[0][0], acc[1][0], 0, 0, 0);              \
        acc[1][0] = MF(afh[1][0], WXL[0][0], acc[1][0], 0, 0, 0);              \
        acc[1][1] = MF(afh[1][0], WXH[1][0], acc[1][1], 0, 0, 0);              \
        acc[1][1] = MF(afl[1][0], WXH[1][0], acc[1][1], 0, 0, 0);              \
        acc[1][1] = MF(afh[1][0], WXL[1][0], acc[1][1], 0, 0, 0);              \
        acc[0][0] = MF(afh[0][1], WXH[0][1], acc[0][0], 0, 0, 0);              \
        acc[0][0] = MF(afl[0][1], WXH[0][1], acc[0][0], 0, 0, 0);              \
        acc[0][0] = MF(afh[0][1], WXL[0][1], acc[0][0], 0, 0, 0);              \
        acc[0][1] = MF(afh[0][1], WXH[1][1], acc[0][1], 0, 0, 0);              \
        acc[0][1] = MF(afl[0][1], WXH[1][1], acc[0][1], 0, 0, 0);              \
        acc[0][1] = MF(afh[0][1], WXL[1][1], acc[0][1], 0, 0, 0);              \
        acc[1][0] = MF(afh[1][1], WXH[0][1], acc[1][0], 0, 0, 0);              \
        acc[1][0] = MF(afl[1][1], WXH[0][1], acc[1][0], 0, 0, 0);              \
        acc[1][0] = MF(afh[1][1], WXL[0][1], acc[1][0], 0, 0, 0);              \
        acc[1][1] = MF(afh[1][1], WXH[1][1], acc[1][1], 0, 0, 0);              \
        acc[1][1] = MF(afl[1][1], WXH[1][1], acc[1][1], 0, 0, 0);              \
        acc[1][1] = MF(afh[1][1], WXL[1][1], acc[1][1], 0, 0, 0);              \
    } while (0)

    // prologue
    ALOAD(aA0, aA1, 0);
    STAGE(0, aA0, aA1);
    ALOAD(aA0, aA1, 1);
    ALOAD(aB0, aB1, 2);
    WLOAD(wAh, wAl, 0);

    for (int kt2 = 0; kt2 < NKTB; kt2 += 2) {
        ITER(kt2,     0, aA0, aA1, wAh, wAl, wBh, wBl);
        ITER(kt2 + 1, 1, aB0, aB1, wBh, wBl, wAh, wAl);
    }

    // epilogue: C/D col=lane&31, row=(g&3)+8*(g>>2)+4*(lane>>5)  [m74/m101]
    float* o = ATOMIC ? dst : dst + (size_t)ks * TOKENS * EXPERTS;
    #pragma unroll
    for (int mi = 0; mi < 2; ++mi)
        #pragma unroll
        for (int n = 0; n < 2; ++n)
            #pragma unroll
            for (int g = 0; g < 16; ++g) {
                const int row = row0 + wm * 64 + mi * 32 + (g & 3) + ((g >> 2) << 3) + ((lane >> 5) << 2);
                const int col = wn * 64 + n * 32 + (lane & 31);
                const size_t idx = (size_t)row * EXPERTS + col;
                if (ATOMIC) atomicAdd(o + idx, acc[mi][n][g]);
                else        o[idx] = acc[mi][n][g];
            }
    #undef ITER
    #undef MF
    #undef ALOAD
    #undef STAGE
    #undef WLOAD
}

// ---------------- fast route with decision margins ----------------
template <int NPART>
__global__ __launch_bounds__(256) void route_margin(const float* __restrict__ p0,
                                                    const float* __restrict__ bias,
                                                    float* __restrict__ out,
                                                    int* __restrict__ cnt,
                                                    int* __restrict__ list) {
    const int lane = threadIdx.x & 63;
    const int t    = blockIdx.x * 4 + (threadIdx.x >> 6);

    float4 lg = *(const float4*)(p0 + (size_t)t * EXPERTS + (lane << 2));
    #pragma unroll
    for (int p = 1; p < NPART; ++p) {
        const float4 l2 = *(const float4*)(p0 + (size_t)p * TOKENS * EXPERTS +
                                           (size_t)t * EXPERTS + (lane << 2));
        lg.x += l2.x; lg.y += l2.y; lg.z += l2.z; lg.w += l2.w;
    }
    const float4 bz = *(const float4*)(bias + (lane << 2));

    const float s0 = 1.f / (1.f + expf(-lg.x));
    const float s1 = 1.f / (1.f + expf(-lg.y));
    const float s2 = 1.f / (1.f + expf(-lg.z));
    const float s3 = 1.f / (1.f + expf(-lg.w));
    const float b0 = s0 + bz.x, b1 = s1 + bz.y, b2 = s2 + bz.z, b3 = s3 + bz.w;

    float hi01 = fmaxf(b0, b1), lo01 = fminf(b0, b1);
    float hi23 = fmaxf(b2, b3), lo23 = fminf(b2, b3);
    float a0v = fmaxf(hi01, hi23);
    float a1v = fmaxf(fminf(hi01, hi23), fmaxf(lo01, lo23));
    #pragma unroll
    for (int off = 1; off < 8; off <<= 1) {
        float o0 = __shfl_xor(a0v, off);
        float o1 = __shfl_xor(a1v, off);
        float n0 = fmaxf(a0v, o0);
        float n1 = fmaxf(fminf(a0v, o0), fmaxf(a1v, o1));
        a0v = n0; a1v = n1;
    }
    const float gscore = a0v + a1v;

    float gsc[8];
    #pragma unroll
    for (int g = 0; g < 8; ++g) gsc[g] = __shfl(gscore, g << 3);

    const int g0 = lane >> 3;
    int myrank = 0;
    float v4 = -1e30f, v5 = -1e30f;
    #pragma unroll
    for (int h = 0; h < 8; ++h) {
        int rk = 0;
        #pragma unroll
        for (int h2 = 0; h2 < 8; ++h2)
            rk += ((gsc[h2] > gsc[h]) || (gsc[h2] == gsc[h] && h2 < h)) ? 1 : 0;
        if (h == g0) myrank = rk;
        if (rk == TOPKG - 1) v4 = gsc[h];
        if (rk == TOPKG)     v5 = gsc[h];
    }
    const bool sel = (myrank < TOPKG);
    const float margin_g = v4 - v5;

    float m0 = sel ? b0 : 0.f;
    float m1 = sel ? b1 : 0.f;
    float m2 = sel ? b2 : 0.f;
    float m3 = sel ? b3 : 0.f;

    float sum = 0.f;
    int myidx = 0; float mysc = 0.f;
    float prev = 0.f, mine = 1e30f;
    #pragma unroll
    for (int rr = 0; rr < TOPK + 1; ++rr) {
        float bv = m0; int bj = 0;
        if (m1 > bv) { bv = m1; bj = 1; }
        if (m2 > bv) { bv = m2; bj = 2; }
        if (m3 > bv) { bv = m3; bj = 3; }
        float bsc = (bj == 0) ? s0 : (bj == 1) ? s1 : (bj == 2) ? s2 : s3;
        int bidx = (lane << 2) | bj;
        #pragma unroll
        for (int off = 1; off < 64; off <<= 1) {
            float ov  = __shfl_xor(bv, off);
            int   oi  = __shfl_xor(bidx, off);
            float osc = __shfl_xor(bsc, off);
            if (ov > bv || (ov == bv && oi < bidx)) { bv = ov; bidx = oi; bsc = osc; }
        }
        if (rr) mine = fminf(mine, prev - bv);
        prev = bv;
        if (rr < TOPK) {
            sum += bsc;
            if (lane == rr) { myidx = bidx; mysc = bsc; }
            if ((bidx >> 2) == lane) {
                const int sl = bidx & 3;
                if      (sl == 0) m0 = -FLT_MAX;
                else if (sl == 1) m1 = -FLT_MAX;
                else if (sl == 2) m2 = -FLT_MAX;
                else              m3 = -FLT_MAX;
            }
        }
    }

    const bool fb = (margin_g < TAU_G) || (mine < TAU_E);
    if (fb) {
        if (lane == 0) { int p = atomicAdd(cnt, 1); if (p < MAXFB) list[p] = t; }
    } else if (lane < TOPK) {
        const size_t base = (size_t)t * TOPK + lane;
        out[base] = (float)myidx;
        out[(size_t)TOKENS * TOPK + base] = mysc / (sum + 1e-20f) * 2.5f;
    }
}

// ---------------- f1: exact f64 logits, ONE EXPERT PER BLOCK ----------------
// Grid 256 (1/CU). Block e stages W[e] in LDS once; 4 waves sweep the n flagged
// tokens (wave wv -> ti = wv, wv+4, ...). Lane-parallel f64 dot + shuffle reduce.
// W read exactly once machine-wide; flagged A rows go LLC-hot immediately.
__global__ __launch_bounds__(256) void fallback_logits(const float* __restrict__ A,
                                                       const float* __restrict__ W,
                                                       const int* __restrict__ cnt,
                                                       const int* __restrict__ list,
                                                       double* __restrict__ lgs) {
    const int n = min(*cnt, MAXFB);
    if (n == 0) return;
    __shared__ float Wsh[HIDDEN];   // 28 KB
    const int e = blockIdx.x;
    const int tid = threadIdx.x;

    const float4* wg = (const float4*)(W + (size_t)e * HIDDEN);
    for (int i = tid; i < HIDDEN / 4; i += 256)
        ((float4*)Wsh)[i] = wg[i];
    __syncthreads();

    const int lane = tid & 63, wv = tid >> 6;
    for (int ti = wv; ti < n; ti += 4) {
        const int t = list[ti];
        const float* ar = A + (size_t)t * HIDDEN;
        double ac = 0.0;
        #pragma unroll 4
        for (int it = 0; it < HIDDEN / 256; ++it) {   // 28 iterations
            const int k = it * 256 + (lane << 2);
            const float4 a4 = *(const float4*)(ar + k);
            const float4 w4 = *(const float4*)&Wsh[k];
            ac = fma((double)a4.x, (double)w4.x, ac);
            ac = fma((double)a4.y, (double)w4.y, ac);
            ac = fma((double)a4.z, (double)w4.z, ac);
            ac = fma((double)a4.w, (double)w4.w, ac);
        }
        #pragma unroll
        for (int off = 32; off; off >>= 1)
            ac += __shfl_xor(ac, off);
        if (lane == 0)
            lgs[(size_t)ti * EXPERTS + e] = ac;
    }
}

// ---------------- f2: exact f64 route for flagged tokens ----------------
__global__ __launch_bounds__(256) void fallback_route(const double* __restrict__ lgs,
                                                      const float* __restrict__ bias,
                                                      const int* __restrict__ cnt,
                                                      const int* __restrict__ list,
                                                      float* __restrict__ out) {
    const int n  = min(*cnt, MAXFB);
    const int ti = blockIdx.x * 4 + (threadIdx.x >> 6);
    if (ti >= n) return;
    const int lane = threadIdx.x & 63;
    const int t = list[ti];

    const double l0 = lgs[(size_t)ti * EXPERTS + (lane << 2)];
    const double l1 = lgs[(size_t)ti * EXPERTS + (lane << 2) + 1];
    const double l2 = lgs[(size_t)ti * EXPERTS + (lane << 2) + 2];
    const double l3 = lgs[(size_t)ti * EXPERTS + (lane << 2) + 3];
    const float4 bzf = *(const float4*)(bias + (lane << 2));

    const double s0 = 1.0 / (1.0 + exp(-l0));
    const double s1 = 1.0 / (1.0 + exp(-l1));
    const double s2 = 1.0 / (1.0 + exp(-l2));
    const double s3 = 1.0 / (1.0 + exp(-l3));
    const double b0 = s0 + (double)bzf.x, b1 = s1 + (double)bzf.y;
    const double b2 = s2 + (double)bzf.z, b3 = s3 + (double)bzf.w;

    double hi01 = fmax(b0, b1), lo01 = fmin(b0, b1);
    double hi23 = fmax(b2, b3), lo23 = fmin(b2, b3);
    double a0v = fmax(hi01, hi23);
    double a1v = fmax(fmin(hi01, hi23), fmax(lo01, lo23));
    #pragma unroll
    for (int off = 1; off < 8; off <<= 1) {
        double o0 = __shfl_xor(a0v, off);
        double o1 = __shfl_xor(a1v, off);
        double n0 = fmax(a0v, o0);
        double n1 = fmax(fmin(a0v, o0), fmax(a1v, o1));
        a0v = n0; a1v = n1;
    }
    const double gscore = a0v + a1v;
    double gsc[8];
    #pragma unroll
    for (int g = 0; g < 8; ++g) gsc[g] = __shfl(gscore, g << 3);
    const int g0 = lane >> 3;
    int rank = 0;
    #pragma unroll
    for (int h = 0; h < 8; ++h)
        rank += ((gsc[h] > gscore) || (gsc[h] == gscore && h < g0)) ? 1 : 0;
    const bool sel = (rank < TOPKG);

    double m0 = sel ? b0 : 0.0;
    double m1 = sel ? b1 : 0.0;
    double m2 = sel ? b2 : 0.0;
    double m3 = sel ? b3 : 0.0;

    double sum = 0.0;
    int myidx = 0; double mysc = 0.0;
    #pragma unroll
    for (int rr = 0; rr < TOPK; ++rr) {
        double bv = m0; int bj = 0;
        if (m1 > bv) { bv = m1; bj = 1; }
        if (m2 > bv) { bv = m2; bj = 2; }
        if (m3 > bv) { bv = m3; bj = 3; }
        double bsc = (bj == 0) ? s0 : (bj == 1) ? s1 : (bj == 2) ? s2 : s3;
        int bidx = (lane << 2) | bj;
        #pragma unroll
        for (int off = 1; off < 64; off <<= 1) {
            double ov  = __shfl_xor(bv, off);
            int    oi  = __shfl_xor(bidx, off);
            double osc = __shfl_xor(bsc, off);
            if (ov > bv || (ov == bv && oi < bidx)) { bv = ov; bidx = oi; bsc = osc; }
        }
        sum += bsc;
        if (lane == rr) { myidx = bidx; mysc = bsc; }
        if ((bidx >> 2) == lane) {
            const int sl = bidx & 3;
            if      (sl == 0) m0 = -DBL_MAX;
            else if (sl == 1) m1 = -DBL_MAX;
            else if (sl == 2) m2 = -DBL_MAX;
            else              m3 = -DBL_MAX;
        }
    }
    if (lane < TOPK) {
        const size_t base = (size_t)t * TOPK + lane;
        out[base] = (float)myidx;
        out[(size_t)TOKENS * TOPK + base] = (float)(mysc / (sum + 1e-20) * 2.5);
    }
}

extern "C" void kernel_launch(void* const* d_in, const int* in_sizes, int n_in,
                              void* d_out, int out_size, void* d_ws, size_t ws_size,
                              hipStream_t stream) {
    const float* hs   = (const float*)d_in[0];
    const float* wt   = (const float*)d_in[1];
    const float* bias = (const float*)d_in[2];
    float* out = (float*)d_out;
    char* ws = (char*)d_ws;

    const size_t LGSZ = (size_t)TOKENS * EXPERTS * 4;     // 8 MB
    const size_t WIMG = (size_t)WIMG_ELEMS * 2;           // 3.67 MB per buffer

    if (ws_size >= KSPLIT * LGSZ + 131072 + 2 * WIMG) {
        // deterministic 4-partial path
        float*  part  = (float*)ws;
        int*    cnt   = (int*)(ws + KSPLIT * LGSZ);
        int*    list  = (int*)(ws + KSPLIT * LGSZ + 256);
        ushort* wsh   = (ushort*)(ws + KSPLIT * LGSZ + 131072);
        ushort* wsl   = (ushort*)(ws + KSPLIT * LGSZ + 131072 + WIMG);
        double* lgs64 = (double*)ws;   // overlays P0 after route

        split_w<<<WIMG_ELEMS / 256, 256, 0, stream>>>(wt, wsh, wsl, cnt);
        logits_mfma<false><<<256, 512, 0, stream>>>(hs, wsh, wsl, part);
        route_margin<KSPLIT><<<TOKENS / 4, 256, 0, stream>>>(part, bias, out, cnt, list);
        fallback_logits<<<EXPERTS, 256, 0, stream>>>(hs, wt, cnt, list, lgs64);
        fallback_route<<<MAXFB / 4, 256, 0, stream>>>(lgs64, bias, cnt, list, out);
    } else {
        // atomic single-buffer path
        float*  logits = (float*)ws;
        int*    cnt    = (int*)(ws + LGSZ);
        int*    list   = (int*)(ws + LGSZ + 256);
        ushort* wsh    = (ushort*)(ws + LGSZ + 131072);
        ushort* wsl    = (ushort*)(ws + LGSZ + 131072 + WIMG);
        double* lgs64  = (double*)ws;

        hipMemsetAsync(logits, 0, LGSZ, stream);
        split_w<<<WIMG_ELEMS / 256, 256, 0, stream>>>(wt, wsh, wsl, cnt);
        logits_mfma<true><<<256, 512, 0, stream>>>(hs, wsh, wsl, logits);
        route_margin<1><<<TOKENS / 4, 256, 0, stream>>>(logits, bias, out, cnt, list);
        fallback_logits<<<EXPERTS, 256, 0, stream>>>(hs, wt, cnt, list, lgs64);
        fallback_route<<<MAXFB / 4, 256, 0, stream>>>(lgs64, bias, cnt, list, out);
    }
}

// Round 11
// 191.955 us; speedup vs baseline: 1.8202x; 1.1041x over previous
//
#include <hip/hip_runtime.h>
#include <float.h>
#include <math.h>

#define TOKENS 8192
#define EXPERTS 256
#define HIDDEN 7168
#define TOPK 8
#define TOPKG 4

#define BM 64
#define BN 256
#define BK 32
#define KSPLIT 4
#define KQ (HIDDEN / KSPLIT)     // 1792
#define NKTB (KQ / BK)           // 56 k-steps per block

#define TAU_E 6.0e-6f
#define TAU_G 1.2e-5f
#define MAXFB 1024

// ---- ws layouts (bytes) ----
// partial path: P0..P3 [0, 32M) | cnt 33554432 | list +256 | WH 33685504 | WL 37355520
// atomic  path: LG [0, 8M) | cnt 8388608 | list +256 | WH 8519680 | WL 12189696
#define WIMG_ELEMS 1835008   // ushorts per buffer: 448 kt16 * 8 cg * 512

typedef __attribute__((ext_vector_type(8))) short bf16x8;
typedef __attribute__((ext_vector_type(16))) float f32x16;

__device__ inline ushort bf16_rne(float x) {
    uint u = __float_as_uint(x);
    return (ushort)((u + 0x7FFFu + ((u >> 16) & 1u)) >> 16);
}
__device__ inline float bf16_tof(ushort h) { return __uint_as_float((uint)h << 16); }

#define CVTPK(lo, hi) ({ uint r_; asm("v_cvt_pk_bf16_f32 %0, %1, %2" : "=v"(r_) : "v"(lo), "v"(hi)); r_; })
__device__ inline float lo16f(uint u) { return __uint_as_float(u << 16); }
__device__ inline float hi16f(uint u) { return __uint_as_float(u & 0xFFFF0000u); }

// Counted-sync barrier (T4): drain only LDS ops; leave global prefetch in flight.
#define BAR() do {                                             \
    asm volatile("s_waitcnt lgkmcnt(0)" ::: "memory");         \
    __builtin_amdgcn_s_barrier();                              \
    __builtin_amdgcn_sched_barrier(0);                         \
} while (0)

// W image, 32x32-MFMA fragment order over the FULL expert dim:
// wh[((kt16*8)+cg)*512 + lane*8 + j] = bf16(W[cg*32+(lane&31)][kt16*16+(lane>>5)*8+j])
__global__ __launch_bounds__(256) void split_w(const float* __restrict__ W,
                                               ushort* __restrict__ wh,
                                               ushort* __restrict__ wl,
                                               int* __restrict__ cnt) {
    if (blockIdx.x == 0 && threadIdx.x == 0) *cnt = 0;
    const int tau  = blockIdx.x * 256 + threadIdx.x;   // [0, 1835008)
    const int j    = tau & 7;
    const int lane = (tau >> 3) & 63;
    const int cg   = (tau >> 9) & 7;
    const int kt16 = tau >> 12;
    const int col  = cg * 32 + (lane & 31);
    const int k    = kt16 * 16 + (lane >> 5) * 8 + j;
    const float w  = W[(size_t)col * HIDDEN + k];
    const ushort h = bf16_rne(w);
    const ushort l = bf16_rne(w - bf16_tof(h));
    wh[tau] = h;
    wl[tau] = l;
}

// ---------------- bf16-split 32x32 MFMA GEMM ----------------
// Grid 512 = 128 mb x 4 ks -> 2 blocks/CU, 16 waves/CU (4/SIMD).
// 512 threads = 8 waves, wave grid (1,8): wave wn owns cols wn*32..+31, all 64
// rows -> W fragments wave-exclusive (no duplication). A via LDS dbuf (cvt_pk
// split); W fragments direct from pre-split L2 image (one ks slice per XCD pair).
template <bool ATOMIC>
__global__ __launch_bounds__(512, 2) void logits_mfma(const float* __restrict__ A,
                                                      const ushort* __restrict__ wh,
                                                      const ushort* __restrict__ wl,
                                                      float* __restrict__ dst) {
    __shared__ ushort Ah[2][BM * BK];   // 4KB per buf
    __shared__ ushort Al[2][BM * BK];

    const int b  = blockIdx.x;
    const int ks = b & 3;
    const int mb = b >> 2;
    const int row0 = mb * BM;

    const int t = threadIdx.x, lane = t & 63, wn = t >> 6;

    // A staging: thread t -> row sr=t>>3, k-quad q=t&7 (4 floats)
    const int sr = t >> 3, q = t & 7;
    const float* Ap = A + (size_t)(row0 + sr) * HIDDEN + (size_t)ks * KQ + q * 4;
    const int sswz = ((sr >> 1) ^ (sr >> 3)) & 3;
    const int sidx = sr * 32 + ((((q >> 1)) ^ sswz) << 3) + (q & 1) * 4;

    // A fragment read indices [mi][kh]
    int fidx[2][2];
    #pragma unroll
    for (int mi = 0; mi < 2; ++mi) {
        const int r = mi * 32 + (lane & 31);
        const int swz = ((r >> 1) ^ (r >> 3)) & 3;
        #pragma unroll
        for (int kh = 0; kh < 2; ++kh)
            fidx[mi][kh] = r * 32 + (((kh * 2 + (lane >> 5)) ^ swz) << 3);
    }

    const int wlanes = lane * 8;

    f32x16 acc[2];
    acc[0] = (f32x16)0.f;
    acc[1] = (f32x16)0.f;

    float4 aA, aB;
    bf16x8 wAh[2], wAl[2], wBh[2], wBl[2];   // [kh]

    #define WLOAD(DH, DL, KTL) do {                                            \
        const size_t wo = ((size_t)((ks * NKTB + (KTL)) * 2) * 8 + wn) * 512 + wlanes; \
        DH[0] = *(const bf16x8*)(wh + wo);                                     \
        DH[1] = *(const bf16x8*)(wh + wo + 4096);                              \
        DL[0] = *(const bf16x8*)(wl + wo);                                     \
        DL[1] = *(const bf16x8*)(wl + wo + 4096);                              \
    } while (0)

    #define STAGE(BB, R) do {                                                  \
        uint h0 = CVTPK(R.x, R.y), h1 = CVTPK(R.z, R.w);                       \
        float q0 = R.x - lo16f(h0), q1 = R.y - hi16f(h0);                      \
        float q2 = R.z - lo16f(h1), q3 = R.w - hi16f(h1);                      \
        uint l0 = CVTPK(q0, q1), l1 = CVTPK(q2, q3);                           \
        *(uint2*)&Ah[BB][sidx] = make_uint2(h0, h1);                           \
        *(uint2*)&Al[BB][sidx] = make_uint2(l0, l1);                           \
    } while (0)

    #define ALOAD(R, KTL) do {                                                 \
        const int ka = ((KTL) < NKTB ? (KTL) : NKTB - 1) * BK;                 \
        R = *(const float4*)(Ap + ka);                                         \
    } while (0)

    #define MF __builtin_amdgcn_mfma_f32_32x32x16_bf16

    #define ITER(KT, BB, X, WXH, WXL, WYH, WYL) do {                           \
        BAR();                                                                 \
        bf16x8 afh[2][2], afl[2][2];                                           \
        afh[0][0] = *(const bf16x8*)&Ah[BB][fidx[0][0]];                       \
        afh[0][1] = *(const bf16x8*)&Ah[BB][fidx[0][1]];                       \
        afh[1][0] = *(const bf16x8*)&Ah[BB][fidx[1][0]];                       \
        afh[1][1] = *(const bf16x8*)&Ah[BB][fidx[1][1]];                       \
        afl[0][0] = *(const bf16x8*)&Al[BB][fidx[0][0]];                       \
        afl[0][1] = *(const bf16x8*)&Al[BB][fidx[0][1]];                       \
        afl[1][0] = *(const bf16x8*)&Al[BB][fidx[1][0]];                       \
        afl[1][1] = *(const bf16x8*)&Al[BB][fidx[1][1]];                       \
        STAGE((BB) ^ 1, X);                                                    \
        ALOAD(X, (KT) + 3);                                                    \
        WLOAD(WYH, WYL, ((KT) + 1 < NKTB ? (KT) + 1 : NKTB - 1));              \
        acc[0] = MF(afh[0][0], WXH[0], acc[0], 0, 0, 0);                       \
        acc[0] = MF(afl[0][0], WXH[0], acc[0], 0, 0, 0);                       \
        acc[0] = MF(afh[0][0], WXL[0], acc[0], 0, 0, 0);                       \
        acc[1] = MF(afh[1][0], WXH[0], acc[1], 0, 0, 0);                       \
        acc[1] = MF(afl[1][0], WXH[0], acc[1], 0, 0, 0);                       \
        acc[1] = MF(afh[1][0], WXL[0], acc[1], 0, 0, 0);                       \
        acc[0] = MF(afh[0][1], WXH[1], acc[0], 0, 0, 0);                       \
        acc[0] = MF(afl[0][1], WXH[1], acc[0], 0, 0, 0);                       \
        acc[0] = MF(afh[0][1], WXL[1], acc[0], 0, 0, 0);                       \
        acc[1] = MF(afh[1][1], WXH[1], acc[1], 0, 0, 0);                       \
        acc[1] = MF(afl[1][1], WXH[1], acc[1], 0, 0, 0);                       \
        acc[1] = MF(afh[1][1], WXL[1], acc[1], 0, 0, 0);                       \
    } while (0)

    // prologue
    ALOAD(aA, 0);
    STAGE(0, aA);
    ALOAD(aA, 1);
    ALOAD(aB, 2);
    WLOAD(wAh, wAl, 0);

    for (int kt2 = 0; kt2 < NKTB; kt2 += 2) {
        ITER(kt2,     0, aA, wAh, wAl, wBh, wBl);
        ITER(kt2 + 1, 1, aB, wBh, wBl, wAh, wAl);
    }

    // epilogue: C/D col=lane&31, row=(g&3)+8*(g>>2)+4*(lane>>5)  [m74/m101]
    float* o = ATOMIC ? dst : dst + (size_t)ks * TOKENS * EXPERTS;
    #pragma unroll
    for (int mi = 0; mi < 2; ++mi)
        #pragma unroll
        for (int g = 0; g < 16; ++g) {
            const int row = row0 + mi * 32 + (g & 3) + ((g >> 2) << 3) + ((lane >> 5) << 2);
            const int col = wn * 32 + (lane & 31);
            const size_t idx = (size_t)row * EXPERTS + col;
            if (ATOMIC) atomicAdd(o + idx, acc[mi][g]);
            else        o[idx] = acc[mi][g];
        }
    #undef ITER
    #undef MF
    #undef ALOAD
    #undef STAGE
    #undef WLOAD
}

// ---------------- fast route with decision margins ----------------
template <int NPART>
__global__ __launch_bounds__(256) void route_margin(const float* __restrict__ p0,
                                                    const float* __restrict__ bias,
                                                    float* __restrict__ out,
                                                    int* __restrict__ cnt,
                                                    int* __restrict__ list) {
    const int lane = threadIdx.x & 63;
    const int t    = blockIdx.x * 4 + (threadIdx.x >> 6);

    float4 lg = *(const float4*)(p0 + (size_t)t * EXPERTS + (lane << 2));
    #pragma unroll
    for (int p = 1; p < NPART; ++p) {
        const float4 l2 = *(const float4*)(p0 + (size_t)p * TOKENS * EXPERTS +
                                           (size_t)t * EXPERTS + (lane << 2));
        lg.x += l2.x; lg.y += l2.y; lg.z += l2.z; lg.w += l2.w;
    }
    const float4 bz = *(const float4*)(bias + (lane << 2));

    const float s0 = 1.f / (1.f + expf(-lg.x));
    const float s1 = 1.f / (1.f + expf(-lg.y));
    const float s2 = 1.f / (1.f + expf(-lg.z));
    const float s3 = 1.f / (1.f + expf(-lg.w));
    const float b0 = s0 + bz.x, b1 = s1 + bz.y, b2 = s2 + bz.z, b3 = s3 + bz.w;

    float hi01 = fmaxf(b0, b1), lo01 = fminf(b0, b1);
    float hi23 = fmaxf(b2, b3), lo23 = fminf(b2, b3);
    float a0v = fmaxf(hi01, hi23);
    float a1v = fmaxf(fminf(hi01, hi23), fmaxf(lo01, lo23));
    #pragma unroll
    for (int off = 1; off < 8; off <<= 1) {
        float o0 = __shfl_xor(a0v, off);
        float o1 = __shfl_xor(a1v, off);
        float n0 = fmaxf(a0v, o0);
        float n1 = fmaxf(fminf(a0v, o0), fmaxf(a1v, o1));
        a0v = n0; a1v = n1;
    }
    const float gscore = a0v + a1v;

    float gsc[8];
    #pragma unroll
    for (int g = 0; g < 8; ++g) gsc[g] = __shfl(gscore, g << 3);

    const int g0 = lane >> 3;
    int myrank = 0;
    float v4 = -1e30f, v5 = -1e30f;
    #pragma unroll
    for (int h = 0; h < 8; ++h) {
        int rk = 0;
        #pragma unroll
        for (int h2 = 0; h2 < 8; ++h2)
            rk += ((gsc[h2] > gsc[h]) || (gsc[h2] == gsc[h] && h2 < h)) ? 1 : 0;
        if (h == g0) myrank = rk;
        if (rk == TOPKG - 1) v4 = gsc[h];
        if (rk == TOPKG)     v5 = gsc[h];
    }
    const bool sel = (myrank < TOPKG);
    const float margin_g = v4 - v5;

    float m0 = sel ? b0 : 0.f;
    float m1 = sel ? b1 : 0.f;
    float m2 = sel ? b2 : 0.f;
    float m3 = sel ? b3 : 0.f;

    float sum = 0.f;
    int myidx = 0; float mysc = 0.f;
    float prev = 0.f, mine = 1e30f;
    #pragma unroll
    for (int rr = 0; rr < TOPK + 1; ++rr) {
        float bv = m0; int bj = 0;
        if (m1 > bv) { bv = m1; bj = 1; }
        if (m2 > bv) { bv = m2; bj = 2; }
        if (m3 > bv) { bv = m3; bj = 3; }
        float bsc = (bj == 0) ? s0 : (bj == 1) ? s1 : (bj == 2) ? s2 : s3;
        int bidx = (lane << 2) | bj;
        #pragma unroll
        for (int off = 1; off < 64; off <<= 1) {
            float ov  = __shfl_xor(bv, off);
            int   oi  = __shfl_xor(bidx, off);
            float osc = __shfl_xor(bsc, off);
            if (ov > bv || (ov == bv && oi < bidx)) { bv = ov; bidx = oi; bsc = osc; }
        }
        if (rr) mine = fminf(mine, prev - bv);
        prev = bv;
        if (rr < TOPK) {
            sum += bsc;
            if (lane == rr) { myidx = bidx; mysc = bsc; }
            if ((bidx >> 2) == lane) {
                const int sl = bidx & 3;
                if      (sl == 0) m0 = -FLT_MAX;
                else if (sl == 1) m1 = -FLT_MAX;
                else if (sl == 2) m2 = -FLT_MAX;
                else              m3 = -FLT_MAX;
            }
        }
    }

    const bool fb = (margin_g < TAU_G) || (mine < TAU_E);
    if (fb) {
        if (lane == 0) { int p = atomicAdd(cnt, 1); if (p < MAXFB) list[p] = t; }
    } else if (lane < TOPK) {
        const size_t base = (size_t)t * TOPK + lane;
        out[base] = (float)myidx;
        out[(size_t)TOKENS * TOPK + base] = mysc / (sum + 1e-20f) * 2.5f;
    }
}

// ---------------- f1: exact f64 logits, ONE EXPERT PER BLOCK ----------------
__global__ __launch_bounds__(256) void fallback_logits(const float* __restrict__ A,
                                                       const float* __restrict__ W,
                                                       const int* __restrict__ cnt,
                                                       const int* __restrict__ list,
                                                       double* __restrict__ lgs) {
    const int n = min(*cnt, MAXFB);
    if (n == 0) return;
    __shared__ float Wsh[HIDDEN];   // 28 KB
    const int e = blockIdx.x;
    const int tid = threadIdx.x;

    const float4* wg = (const float4*)(W + (size_t)e * HIDDEN);
    for (int i = tid; i < HIDDEN / 4; i += 256)
        ((float4*)Wsh)[i] = wg[i];
    __syncthreads();

    const int lane = tid & 63, wv = tid >> 6;
    for (int ti = wv; ti < n; ti += 4) {
        const int t = list[ti];
        const float* ar = A + (size_t)t * HIDDEN;
        double ac = 0.0;
        #pragma unroll 4
        for (int it = 0; it < HIDDEN / 256; ++it) {   // 28 iterations
            const int k = it * 256 + (lane << 2);
            const float4 a4 = *(const float4*)(ar + k);
            const float4 w4 = *(const float4*)&Wsh[k];
            ac = fma((double)a4.x, (double)w4.x, ac);
            ac = fma((double)a4.y, (double)w4.y, ac);
            ac = fma((double)a4.z, (double)w4.z, ac);
            ac = fma((double)a4.w, (double)w4.w, ac);
        }
        #pragma unroll
        for (int off = 32; off; off >>= 1)
            ac += __shfl_xor(ac, off);
        if (lane == 0)
            lgs[(size_t)ti * EXPERTS + e] = ac;
    }
}

// ---------------- f2: exact f64 route for flagged tokens ----------------
__global__ __launch_bounds__(256) void fallback_route(const double* __restrict__ lgs,
                                                      const float* __restrict__ bias,
                                                      const int* __restrict__ cnt,
                                                      const int* __restrict__ list,
                                                      float* __restrict__ out) {
    const int n  = min(*cnt, MAXFB);
    const int ti = blockIdx.x * 4 + (threadIdx.x >> 6);
    if (ti >= n) return;
    const int lane = threadIdx.x & 63;
    const int t = list[ti];

    const double l0 = lgs[(size_t)ti * EXPERTS + (lane << 2)];
    const double l1 = lgs[(size_t)ti * EXPERTS + (lane << 2) + 1];
    const double l2 = lgs[(size_t)ti * EXPERTS + (lane << 2) + 2];
    const double l3 = lgs[(size_t)ti * EXPERTS + (lane << 2) + 3];
    const float4 bzf = *(const float4*)(bias + (lane << 2));

    const double s0 = 1.0 / (1.0 + exp(-l0));
    const double s1 = 1.0 / (1.0 + exp(-l1));
    const double s2 = 1.0 / (1.0 + exp(-l2));
    const double s3 = 1.0 / (1.0 + exp(-l3));
    const double b0 = s0 + (double)bzf.x, b1 = s1 + (double)bzf.y;
    const double b2 = s2 + (double)bzf.z, b3 = s3 + (double)bzf.w;

    double hi01 = fmax(b0, b1), lo01 = fmin(b0, b1);
    double hi23 = fmax(b2, b3), lo23 = fmin(b2, b3);
    double a0v = fmax(hi01, hi23);
    double a1v = fmax(fmin(hi01, hi23), fmax(lo01, lo23));
    #pragma unroll
    for (int off = 1; off < 8; off <<= 1) {
        double o0 = __shfl_xor(a0v, off);
        double o1 = __shfl_xor(a1v, off);
        double n0 = fmax(a0v, o0);
        double n1 = fmax(fmin(a0v, o0), fmax(a1v, o1));
        a0v = n0; a1v = n1;
    }
    const double gscore = a0v + a1v;
    double gsc[8];
    #pragma unroll
    for (int g = 0; g < 8; ++g) gsc[g] = __shfl(gscore, g << 3);
    const int g0 = lane >> 3;
    int rank = 0;
    #pragma unroll
    for (int h = 0; h < 8; ++h)
        rank += ((gsc[h] > gscore) || (gsc[h] == gscore && h < g0)) ? 1 : 0;
    const bool sel = (rank < TOPKG);

    double m0 = sel ? b0 : 0.0;
    double m1 = sel ? b1 : 0.0;
    double m2 = sel ? b2 : 0.0;
    double m3 = sel ? b3 : 0.0;

    double sum = 0.0;
    int myidx = 0; double mysc = 0.0;
    #pragma unroll
    for (int rr = 0; rr < TOPK; ++rr) {
        double bv = m0; int bj = 0;
        if (m1 > bv) { bv = m1; bj = 1; }
        if (m2 > bv) { bv = m2; bj = 2; }
        if (m3 > bv) { bv = m3; bj = 3; }
        double bsc = (bj == 0) ? s0 : (bj == 1) ? s1 : (bj == 2) ? s2 : s3;
        int bidx = (lane << 2) | bj;
        #pragma unroll
        for (int off = 1; off < 64; off <<= 1) {
            double ov  = __shfl_xor(bv, off);
            int    oi  = __shfl_xor(bidx, off);
            double osc = __shfl_xor(bsc, off);
            if (ov > bv || (ov == bv && oi < bidx)) { bv = ov; bidx = oi; bsc = osc; }
        }
        sum += bsc;
        if (lane == rr) { myidx = bidx; mysc = bsc; }
        if ((bidx >> 2) == lane) {
            const int sl = bidx & 3;
            if      (sl == 0) m0 = -DBL_MAX;
            else if (sl == 1) m1 = -DBL_MAX;
            else if (sl == 2) m2 = -DBL_MAX;
            else              m3 = -DBL_MAX;
        }
    }
    if (lane < TOPK) {
        const size_t base = (size_t)t * TOPK + lane;
        out[base] = (float)myidx;
        out[(size_t)TOKENS * TOPK + base] = (float)(mysc / (sum + 1e-20) * 2.5);
    }
}

extern "C" void kernel_launch(void* const* d_in, const int* in_sizes, int n_in,
                              void* d_out, int out_size, void* d_ws, size_t ws_size,
                              hipStream_t stream) {
    const float* hs   = (const float*)d_in[0];
    const float* wt   = (const float*)d_in[1];
    const float* bias = (const float*)d_in[2];
    float* out = (float*)d_out;
    char* ws = (char*)d_ws;

    const size_t LGSZ = (size_t)TOKENS * EXPERTS * 4;     // 8 MB
    const size_t WIMG = (size_t)WIMG_ELEMS * 2;           // 3.67 MB per buffer
    const int NBLK = (TOKENS / BM) * KSPLIT;              // 512

    if (ws_size >= KSPLIT * LGSZ + 131072 + 2 * WIMG) {
        // deterministic 4-partial path
        float*  part  = (float*)ws;
        int*    cnt   = (int*)(ws + KSPLIT * LGSZ);
        int*    list  = (int*)(ws + KSPLIT * LGSZ + 256);
        ushort* wsh   = (ushort*)(ws + KSPLIT * LGSZ + 131072);
        ushort* wsl   = (ushort*)(ws + KSPLIT * LGSZ + 131072 + WIMG);
        double* lgs64 = (double*)ws;   // overlays P0 after route

        split_w<<<WIMG_ELEMS / 256, 256, 0, stream>>>(wt, wsh, wsl, cnt);
        logits_mfma<false><<<NBLK, 512, 0, stream>>>(hs, wsh, wsl, part);
        route_margin<KSPLIT><<<TOKENS / 4, 256, 0, stream>>>(part, bias, out, cnt, list);
        fallback_logits<<<EXPERTS, 256, 0, stream>>>(hs, wt, cnt, list, lgs64);
        fallback_route<<<MAXFB / 4, 256, 0, stream>>>(lgs64, bias, cnt, list, out);
    } else {
        // atomic single-buffer path
        float*  logits = (float*)ws;
        int*    cnt    = (int*)(ws + LGSZ);
        int*    list   = (int*)(ws + LGSZ + 256);
        ushort* wsh    = (ushort*)(ws + LGSZ + 131072);
        ushort* wsl    = (ushort*)(ws + LGSZ + 131072 + WIMG);
        double* lgs64  = (double*)ws;

        hipMemsetAsync(logits, 0, LGSZ, stream);
        split_w<<<WIMG_ELEMS / 256, 256, 0, stream>>>(wt, wsh, wsl, cnt);
        logits_mfma<true><<<NBLK, 512, 0, stream>>>(hs, wsh, wsl, logits);
        route_margin<1><<<TOKENS / 4, 256, 0, stream>>>(logits, bias, out, cnt, list);
        fallback_logits<<<EXPERTS, 256, 0, stream>>>(hs, wt, cnt, list, lgs64);
        fallback_route<<<MAXFB / 4, 256, 0, stream>>>(lgs64, bias, cnt, list, out);
    }
}